// Round 3
// baseline (1129.058 us; speedup 1.0000x reference)
//
#include <hip/hip_runtime.h>
#include <math.h>

#define RES   1024
#define FEATC 12
#define CBN   32
#define H_IMG 1080
#define W_IMG 1920
#define NPIX  (H_IMG * W_IMG)

// ---------------- shared device helpers ----------------

__device__ __forceinline__ void face_uv(float x, float y, float z,
                                        int& face, float& ma, float& u, float& v)
{
    const float ax = fabsf(x), ay = fabsf(y), az = fabsf(z);
    const bool is_x = (ax >= ay) && (ax >= az);
    const bool is_y = (!is_x) && (ay >= az);
    if (is_x) {
        face = (x >= 0.0f) ? 0 : 1;
        ma = ax; u = (x >= 0.0f) ? -z : z; v = -y;
    } else if (is_y) {
        face = (y >= 0.0f) ? 2 : 3;
        ma = ay; u = x; v = (y >= 0.0f) ? z : -z;
    } else {
        face = (z >= 0.0f) ? 4 : 5;
        ma = az; u = (z >= 0.0f) ? x : -x; v = -y;
    }
}

// Full per-pixel pipeline given staged LDS params. Math identical to the
// round-2 passing kernel (elementwise-rounded sample path; fp64-exact argmin).
__device__ __forceinline__ void shade_pixel(
    int i,
    const float* __restrict__ rays_d,
    const float* __restrict__ cube,
    const float* sW1, const float* sb1,
    const float* sW2, const float* sb2,
    const float* sW3, const float* sb3,
    const float* sCB, const double* sCN,
    float* __restrict__ out)
{
    const float x = rays_d[3 * i + 0];
    const float y = rays_d[3 * i + 1];
    const float z = rays_d[3 * i + 2];

    int face; float ma, u, v;
    face_uv(x, y, z, face, ma, u, v);

    const float denom = __fadd_rn(ma, 1e-9f);
    const float s = __fsub_rn(__fmul_rn(__fmul_rn(__fadd_rn(__fdiv_rn(u, denom), 1.0f), 0.5f), (float)RES), 0.5f);
    const float t = __fsub_rn(__fmul_rn(__fmul_rn(__fadd_rn(__fdiv_rn(v, denom), 1.0f), 0.5f), (float)RES), 0.5f);

    const float x0f = floorf(s);
    const float y0f = floorf(t);
    const float fx = __fsub_rn(s, x0f);
    const float fy = __fsub_rn(t, y0f);

    int x0i = (int)x0f; x0i = min(max(x0i, 0), RES - 1);
    int x1i = min(x0i + 1, RES - 1);
    int y0i = (int)y0f; y0i = min(max(y0i, 0), RES - 1);
    int y1i = min(y0i + 1, RES - 1);

    const size_t fbase = (size_t)face * RES * RES;
    const float4* p00 = (const float4*)(cube + (fbase + (size_t)y0i * RES + x0i) * FEATC);
    const float4* p01 = (const float4*)(cube + (fbase + (size_t)y0i * RES + x1i) * FEATC);
    const float4* p10 = (const float4*)(cube + (fbase + (size_t)y1i * RES + x0i) * FEATC);
    const float4* p11 = (const float4*)(cube + (fbase + (size_t)y1i * RES + x1i) * FEATC);

    float c00[FEATC], c01[FEATC], c10[FEATC], c11[FEATC];
    #pragma unroll
    for (int q4 = 0; q4 < 3; ++q4) {
        float4 a = p00[q4]; c00[4*q4+0]=a.x; c00[4*q4+1]=a.y; c00[4*q4+2]=a.z; c00[4*q4+3]=a.w;
        float4 b = p01[q4]; c01[4*q4+0]=b.x; c01[4*q4+1]=b.y; c01[4*q4+2]=b.z; c01[4*q4+3]=b.w;
        float4 c = p10[q4]; c10[4*q4+0]=c.x; c10[4*q4+1]=c.y; c10[4*q4+2]=c.z; c10[4*q4+3]=c.w;
        float4 dd= p11[q4]; c11[4*q4+0]=dd.x;c11[4*q4+1]=dd.y;c11[4*q4+2]=dd.z;c11[4*q4+3]=dd.w;
    }

    const float omfx = __fsub_rn(1.0f, fx);
    const float omfy = __fsub_rn(1.0f, fy);
    float feat[FEATC];
    double featd[FEATC];
    #pragma unroll
    for (int k = 0; k < FEATC; ++k) {
        const float top = __fadd_rn(__fmul_rn(c00[k], omfx), __fmul_rn(c01[k], fx));
        const float bot = __fadd_rn(__fmul_rn(c10[k], omfx), __fmul_rn(c11[k], fx));
        feat[k] = __fadd_rn(__fmul_rn(top, omfy), __fmul_rn(bot, fy));
        featd[k] = (double)feat[k];
    }

    // argmin_j (||c_j||^2 - 2 f.c_j) in fp64 — exact decision, identical
    // argmin to round-2's fp64 diff-form (||f||^2 is j-invariant).
    int best = 0;
    double bestd = 1e300;
    for (int j = 0; j < CBN; ++j) {
        double dot = 0.0;
        #pragma unroll
        for (int k = 0; k < FEATC; ++k)
            dot = fma(featd[k], (double)sCB[j * FEATC + k], dot);
        const double d2 = fma(-2.0, dot, sCN[j]);
        if (d2 < bestd) { bestd = d2; best = j; }
    }

    float hin[15];
    #pragma unroll
    for (int k = 0; k < FEATC; ++k)
        hin[k] = __fadd_rn(feat[k], __fsub_rn(sCB[best * FEATC + k], feat[k]));
    hin[12] = x; hin[13] = y; hin[14] = z;

    // j-outer so LDS weight reads are contiguous (ds_read_b128-friendly);
    // per-k accumulation order (j ascending) matches the round-2 kernel.
    float h1[32];
    #pragma unroll
    for (int k = 0; k < 32; ++k) h1[k] = sb1[k];
    #pragma unroll
    for (int j = 0; j < 15; ++j) {
        const float a = hin[j];
        #pragma unroll
        for (int k = 0; k < 32; ++k) h1[k] += a * sW1[j * 32 + k];
    }
    #pragma unroll
    for (int k = 0; k < 32; ++k) h1[k] = fmaxf(h1[k], 0.0f);

    float h2[32];
    #pragma unroll
    for (int k = 0; k < 32; ++k) h2[k] = sb2[k];
    #pragma unroll
    for (int j = 0; j < 32; ++j) {
        const float a = h1[j];
        #pragma unroll
        for (int k = 0; k < 32; ++k) h2[k] += a * sW2[j * 32 + k];
    }
    #pragma unroll
    for (int k = 0; k < 32; ++k) h2[k] = fmaxf(h2[k], 0.0f);

    #pragma unroll
    for (int c = 0; c < 3; ++c) {
        float a = sb3[c];
        #pragma unroll
        for (int j = 0; j < 32; ++j) a += h2[j] * sW3[j * 3 + c];
        float r = 1.0f / (1.0f + expf(-a));
        r = fminf(fmaxf(r, 0.0f), 1.0f);
        out[(size_t)c * NPIX + i] = r;
    }
}

// ---------------- pass 0: zero the compaction counter ----------------

__global__ void zero_counter(int* __restrict__ counter) {
    if (threadIdx.x == 0 && blockIdx.x == 0) *counter = 0;
}

// ---------------- pass A: zero inactive outputs + compact actives ----------------

__global__ __launch_bounds__(256) void prep_kernel(
    const int* __restrict__ mask,
    float*     __restrict__ out,
    int*       __restrict__ counter,
    int*       __restrict__ list)
{
    const int i = blockIdx.x * blockDim.x + threadIdx.x;
    if (i >= NPIX) return;
    const bool active = (mask[i] != 0);
    if (!active) {
        out[0 * NPIX + i] = 0.0f;
        out[1 * NPIX + i] = 0.0f;
        out[2 * NPIX + i] = 0.0f;
    } else {
        // compiler wave-aggregates this into one atomic per wave (m20)
        const int pos = atomicAdd(counter, 1);
        list[pos] = i;
    }
}

// ---------------- pass B: heavy pipeline on compacted actives ----------------

__global__ __launch_bounds__(256) void sky_main(
    const float* __restrict__ rays_d,
    const float* __restrict__ cube,
    const float* __restrict__ cb,
    const float* __restrict__ W1, const float* __restrict__ b1,
    const float* __restrict__ W2, const float* __restrict__ b2,
    const float* __restrict__ W3, const float* __restrict__ b3,
    const int*   __restrict__ counter,
    const int*   __restrict__ list,
    float*       __restrict__ out)
{
    __shared__ float  sW1[15 * 32];
    __shared__ float  sb1[32];
    __shared__ float  sW2[32 * 32];
    __shared__ float  sb2[32];
    __shared__ float  sW3[32 * 3];
    __shared__ float  sb3[3];
    __shared__ float  sCB[CBN * FEATC];
    __shared__ double sCN[CBN];

    for (int t = threadIdx.x; t < 15 * 32; t += blockDim.x) sW1[t] = W1[t];
    for (int t = threadIdx.x; t < 32;      t += blockDim.x) sb1[t] = b1[t];
    for (int t = threadIdx.x; t < 32 * 32; t += blockDim.x) sW2[t] = W2[t];
    for (int t = threadIdx.x; t < 32;      t += blockDim.x) sb2[t] = b2[t];
    for (int t = threadIdx.x; t < 32 * 3;  t += blockDim.x) sW3[t] = W3[t];
    for (int t = threadIdx.x; t < 3;       t += blockDim.x) sb3[t] = b3[t];
    for (int t = threadIdx.x; t < CBN * FEATC; t += blockDim.x) sCB[t] = cb[t];
    if (threadIdx.x < CBN) {
        double sum = 0.0;
        #pragma unroll
        for (int k = 0; k < FEATC; ++k) {
            const double c = (double)cb[threadIdx.x * FEATC + k];
            sum = fma(c, c, sum);
        }
        sCN[threadIdx.x] = sum;
    }
    __syncthreads();

    const int total = *counter;
    const int stride = gridDim.x * blockDim.x;
    for (int t = blockIdx.x * blockDim.x + threadIdx.x; t < total; t += stride) {
        const int i = list[t];
        shade_pixel(i, rays_d, cube, sW1, sb1, sW2, sb2, sW3, sb3, sCB, sCN, out);
    }
}

// ---------------- fallback: monolithic (round-2 proven) ----------------

__global__ __launch_bounds__(256) void sky_mono(
    const float* __restrict__ rays_d,
    const int*   __restrict__ mask,
    const float* __restrict__ cube,
    const float* __restrict__ cb,
    const float* __restrict__ W1, const float* __restrict__ b1,
    const float* __restrict__ W2, const float* __restrict__ b2,
    const float* __restrict__ W3, const float* __restrict__ b3,
    float*       __restrict__ out)
{
    __shared__ float  sW1[15 * 32];
    __shared__ float  sb1[32];
    __shared__ float  sW2[32 * 32];
    __shared__ float  sb2[32];
    __shared__ float  sW3[32 * 3];
    __shared__ float  sb3[3];
    __shared__ float  sCB[CBN * FEATC];
    __shared__ double sCN[CBN];

    for (int t = threadIdx.x; t < 15 * 32; t += blockDim.x) sW1[t] = W1[t];
    for (int t = threadIdx.x; t < 32;      t += blockDim.x) sb1[t] = b1[t];
    for (int t = threadIdx.x; t < 32 * 32; t += blockDim.x) sW2[t] = W2[t];
    for (int t = threadIdx.x; t < 32;      t += blockDim.x) sb2[t] = b2[t];
    for (int t = threadIdx.x; t < 32 * 3;  t += blockDim.x) sW3[t] = W3[t];
    for (int t = threadIdx.x; t < 3;       t += blockDim.x) sb3[t] = b3[t];
    for (int t = threadIdx.x; t < CBN * FEATC; t += blockDim.x) sCB[t] = cb[t];
    if (threadIdx.x < CBN) {
        double sum = 0.0;
        #pragma unroll
        for (int k = 0; k < FEATC; ++k) {
            const double c = (double)cb[threadIdx.x * FEATC + k];
            sum = fma(c, c, sum);
        }
        sCN[threadIdx.x] = sum;
    }
    __syncthreads();

    const int i = blockIdx.x * blockDim.x + threadIdx.x;
    if (i >= NPIX) return;
    if (mask[i] == 0) {
        out[0 * NPIX + i] = 0.0f;
        out[1 * NPIX + i] = 0.0f;
        out[2 * NPIX + i] = 0.0f;
        return;
    }
    shade_pixel(i, rays_d, cube, sW1, sb1, sW2, sb2, sW3, sb3, sCB, sCN, out);
}

// ---------------- launch ----------------

extern "C" void kernel_launch(void* const* d_in, const int* in_sizes, int n_in,
                              void* d_out, int out_size, void* d_ws, size_t ws_size,
                              hipStream_t stream) {
    const float* rays_d = (const float*)d_in[0];
    const int*   mask   = (const int*)d_in[1];
    const float* cube   = (const float*)d_in[2];
    const float* cb     = (const float*)d_in[3];
    const float* W1     = (const float*)d_in[4];
    const float* b1     = (const float*)d_in[5];
    const float* W2     = (const float*)d_in[6];
    const float* b2     = (const float*)d_in[7];
    const float* W3     = (const float*)d_in[8];
    const float* b3     = (const float*)d_in[9];
    float* out = (float*)d_out;

    const size_t ws_needed = 16 + (size_t)NPIX * sizeof(int);
    const int block = 256;

    if (ws_size >= ws_needed) {
        int* counter = (int*)d_ws;
        int* list    = (int*)((char*)d_ws + 16);

        zero_counter<<<1, 64, 0, stream>>>(counter);

        const int gridA = (NPIX + block - 1) / block;  // 8100
        prep_kernel<<<gridA, block, 0, stream>>>(mask, out, counter, list);

        const int gridB = 4096;  // grid-stride covers any count
        sky_main<<<gridB, block, 0, stream>>>(rays_d, cube, cb,
                                              W1, b1, W2, b2, W3, b3,
                                              counter, list, out);
    } else {
        const int grid = (NPIX + block - 1) / block;
        sky_mono<<<grid, block, 0, stream>>>(rays_d, mask, cube, cb,
                                             W1, b1, W2, b2, W3, b3, out);
    }
}

// Round 4
// 771.034 us; speedup vs baseline: 1.4643x; 1.4643x over previous
//
#include <hip/hip_runtime.h>
#include <math.h>

#define RES   1024
#define FEATC 12
#define CBN   32
#define H_IMG 1080
#define W_IMG 1920
#define NPIX  (H_IMG * W_IMG)
#define SEG   2048          // pixels per block
#define PPT   (SEG / 256)   // compaction rounds per block

// Round-2 proven per-pixel pipeline (verbatim math: elementwise-rounded
// sample path, fp64 diff-form argmin, k-outer MLP). Measured 96 VGPR.
__device__ __forceinline__ void shade_pixel(
    int i,
    const float* __restrict__ rays_d,
    const float* __restrict__ cube,
    const float* sW1, const float* sb1,
    const float* sW2, const float* sb2,
    const float* sW3, const float* sb3,
    const float* sCB,
    float* __restrict__ out)
{
    const float x = rays_d[3 * i + 0];
    const float y = rays_d[3 * i + 1];
    const float z = rays_d[3 * i + 2];

    const float ax = fabsf(x), ay = fabsf(y), az = fabsf(z);
    const bool is_x = (ax >= ay) && (ax >= az);
    const bool is_y = (!is_x) && (ay >= az);

    int face; float ma, u, v;
    if (is_x) {
        face = (x >= 0.0f) ? 0 : 1;
        ma = ax; u = (x >= 0.0f) ? -z : z; v = -y;
    } else if (is_y) {
        face = (y >= 0.0f) ? 2 : 3;
        ma = ay; u = x; v = (y >= 0.0f) ? z : -z;
    } else {
        face = (z >= 0.0f) ? 4 : 5;
        ma = az; u = (z >= 0.0f) ? x : -x; v = -y;
    }

    const float denom = __fadd_rn(ma, 1e-9f);
    const float s = __fsub_rn(__fmul_rn(__fmul_rn(__fadd_rn(__fdiv_rn(u, denom), 1.0f), 0.5f), (float)RES), 0.5f);
    const float t = __fsub_rn(__fmul_rn(__fmul_rn(__fadd_rn(__fdiv_rn(v, denom), 1.0f), 0.5f), (float)RES), 0.5f);

    const float x0f = floorf(s);
    const float y0f = floorf(t);
    const float fx = __fsub_rn(s, x0f);
    const float fy = __fsub_rn(t, y0f);

    int x0i = (int)x0f; x0i = min(max(x0i, 0), RES - 1);
    int x1i = min(x0i + 1, RES - 1);
    int y0i = (int)y0f; y0i = min(max(y0i, 0), RES - 1);
    int y1i = min(y0i + 1, RES - 1);

    const size_t fbase = (size_t)face * RES * RES;
    const float4* p00 = (const float4*)(cube + (fbase + (size_t)y0i * RES + x0i) * FEATC);
    const float4* p01 = (const float4*)(cube + (fbase + (size_t)y0i * RES + x1i) * FEATC);
    const float4* p10 = (const float4*)(cube + (fbase + (size_t)y1i * RES + x0i) * FEATC);
    const float4* p11 = (const float4*)(cube + (fbase + (size_t)y1i * RES + x1i) * FEATC);

    float c00[FEATC], c01[FEATC], c10[FEATC], c11[FEATC];
    #pragma unroll
    for (int q4 = 0; q4 < 3; ++q4) {
        float4 a = p00[q4]; c00[4*q4+0]=a.x; c00[4*q4+1]=a.y; c00[4*q4+2]=a.z; c00[4*q4+3]=a.w;
        float4 b = p01[q4]; c01[4*q4+0]=b.x; c01[4*q4+1]=b.y; c01[4*q4+2]=b.z; c01[4*q4+3]=b.w;
        float4 c = p10[q4]; c10[4*q4+0]=c.x; c10[4*q4+1]=c.y; c10[4*q4+2]=c.z; c10[4*q4+3]=c.w;
        float4 dd= p11[q4]; c11[4*q4+0]=dd.x;c11[4*q4+1]=dd.y;c11[4*q4+2]=dd.z;c11[4*q4+3]=dd.w;
    }

    const float omfx = __fsub_rn(1.0f, fx);
    const float omfy = __fsub_rn(1.0f, fy);
    float feat[FEATC];
    #pragma unroll
    for (int k = 0; k < FEATC; ++k) {
        const float top = __fadd_rn(__fmul_rn(c00[k], omfx), __fmul_rn(c01[k], fx));
        const float bot = __fadd_rn(__fmul_rn(c10[k], omfx), __fmul_rn(c11[k], fx));
        feat[k] = __fadd_rn(__fmul_rn(top, omfy), __fmul_rn(bot, fy));
    }

    // argmin in fp64: exact decision given the (bit-matched) fp32 feat
    int best = 0;
    double bestd = 1e300;
    for (int j = 0; j < CBN; ++j) {
        double d2 = 0.0;
        #pragma unroll
        for (int k = 0; k < FEATC; ++k) {
            const double diff = (double)feat[k] - (double)sCB[j * FEATC + k];
            d2 += diff * diff;
        }
        if (d2 < bestd) { bestd = d2; best = j; }
    }

    float hin[15];
    #pragma unroll
    for (int k = 0; k < FEATC; ++k)
        hin[k] = __fadd_rn(feat[k], __fsub_rn(sCB[best * FEATC + k], feat[k]));
    hin[12] = x; hin[13] = y; hin[14] = z;

    float h1[32];
    #pragma unroll
    for (int k = 0; k < 32; ++k) {
        float a = sb1[k];
        #pragma unroll
        for (int j = 0; j < 15; ++j) a += hin[j] * sW1[j * 32 + k];
        h1[k] = fmaxf(a, 0.0f);
    }

    float h2[32];
    #pragma unroll
    for (int k = 0; k < 32; ++k) {
        float a = sb2[k];
        #pragma unroll
        for (int j = 0; j < 32; ++j) a += h1[j] * sW2[j * 32 + k];
        h2[k] = fmaxf(a, 0.0f);
    }

    #pragma unroll
    for (int c = 0; c < 3; ++c) {
        float a = sb3[c];
        #pragma unroll
        for (int j = 0; j < 32; ++j) a += h2[j] * sW3[j * 3 + c];
        float r = 1.0f / (1.0f + expf(-a));
        r = fminf(fmaxf(r, 0.0f), 1.0f);
        out[(size_t)c * NPIX + i] = r;
    }
}

__global__ __launch_bounds__(256) void sky_fused(
    const float* __restrict__ rays_d,   // [NPIX,3]
    const int*   __restrict__ mask,     // [NPIX]
    const float* __restrict__ cube,     // [6,RES,RES,12]
    const float* __restrict__ cb,       // [32,12]
    const float* __restrict__ W1, const float* __restrict__ b1,
    const float* __restrict__ W2, const float* __restrict__ b2,
    const float* __restrict__ W3, const float* __restrict__ b3,
    float*       __restrict__ out)      // [3,NPIX]
{
    __shared__ float sW1[15 * 32];
    __shared__ float sb1[32];
    __shared__ float sW2[32 * 32];
    __shared__ float sb2[32];
    __shared__ float sW3[32 * 3];
    __shared__ float sb3[3];
    __shared__ float sCB[CBN * FEATC];
    __shared__ int   sList[SEG];
    __shared__ int   sWsum[4];

    for (int t = threadIdx.x; t < 15 * 32; t += blockDim.x) sW1[t] = W1[t];
    for (int t = threadIdx.x; t < 32;      t += blockDim.x) sb1[t] = b1[t];
    for (int t = threadIdx.x; t < 32 * 32; t += blockDim.x) sW2[t] = W2[t];
    for (int t = threadIdx.x; t < 32;      t += blockDim.x) sb2[t] = b2[t];
    for (int t = threadIdx.x; t < 32 * 3;  t += blockDim.x) sW3[t] = W3[t];
    for (int t = threadIdx.x; t < 3;       t += blockDim.x) sb3[t] = b3[t];
    for (int t = threadIdx.x; t < CBN * FEATC; t += blockDim.x) sCB[t] = cb[t];
    __syncthreads();

    const int tid  = threadIdx.x;
    const int lane = tid & 63;
    const int wid  = tid >> 6;
    const int seg0 = blockIdx.x * SEG;

    // ---- phase 1: block compaction (ascending order), zero inactive outs ----
    int nAct = 0;
    #pragma unroll
    for (int r = 0; r < PPT; ++r) {
        const int i = seg0 + r * 256 + tid;   // coalesced
        bool act = false;
        if (i < NPIX) {
            act = (mask[i] != 0);
            if (!act) {
                out[0 * NPIX + i] = 0.0f;
                out[1 * NPIX + i] = 0.0f;
                out[2 * NPIX + i] = 0.0f;
            }
        }
        const unsigned long long bal = __ballot(act);
        const int rank = __popcll(bal & ((1ull << lane) - 1ull));
        if (lane == 0) sWsum[wid] = (int)__popcll(bal);
        __syncthreads();
        int woff = 0;
        #pragma unroll
        for (int w = 0; w < 4; ++w) woff += (w < wid) ? sWsum[w] : 0;
        const int wtot = sWsum[0] + sWsum[1] + sWsum[2] + sWsum[3];
        if (act) sList[nAct + woff + rank] = i;
        nAct += wtot;
        __syncthreads();
    }

    // ---- phase 2: shade packed actives (near-100% lane utilization) ----
    for (int t = tid; t < nAct; t += 256) {
        shade_pixel(sList[t], rays_d, cube, sW1, sb1, sW2, sb2, sW3, sb3, sCB, out);
    }
}

extern "C" void kernel_launch(void* const* d_in, const int* in_sizes, int n_in,
                              void* d_out, int out_size, void* d_ws, size_t ws_size,
                              hipStream_t stream) {
    const float* rays_d = (const float*)d_in[0];
    const int*   mask   = (const int*)d_in[1];
    const float* cube   = (const float*)d_in[2];
    const float* cb     = (const float*)d_in[3];
    const float* W1     = (const float*)d_in[4];
    const float* b1     = (const float*)d_in[5];
    const float* W2     = (const float*)d_in[6];
    const float* b2     = (const float*)d_in[7];
    const float* W3     = (const float*)d_in[8];
    const float* b3     = (const float*)d_in[9];
    float* out = (float*)d_out;

    const int grid = (NPIX + SEG - 1) / SEG;  // 1013
    sky_fused<<<grid, 256, 0, stream>>>(rays_d, mask, cube, cb,
                                        W1, b1, W2, b2, W3, b3, out);
}